// Round 10
// baseline (243.851 us; speedup 1.0000x reference)
//
#include <hip/hip_runtime.h>
#include <hip/hip_bf16.h>

#define T_LEN 1024
#define NH    16
#define CH    64
#define LSTR  64        // Q-prologue LDS row stride in shorts (128 B)
#define FSTR  520       // fragment stride in shorts (512 + 8 pad)
#define VOFF  (8 * FSTR)   // V-region offset within a buffer (shorts)

typedef __attribute__((ext_vector_type(8))) short short8;
typedef __attribute__((ext_vector_type(4))) float floatx4;
typedef unsigned long long u64;

__device__ __forceinline__ short f2bf(float x) {
    __hip_bfloat16 b = __float2bfloat16(x);   // RNE (prologue-only scalar path)
    return *(short*)&b;
}
// HW packed conversion: dst.lo16 = bf16(lo), dst.hi16 = bf16(hi).
__device__ __forceinline__ unsigned cvt_pk_bf16(float lo, float hi) {
    unsigned r;
    asm("v_cvt_pk_bf16_f32 %0, %1, %2" : "=v"(r) : "v"(lo), "v"(hi));
    return r;
}
// XOR block-swizzle for the Q prologue tile (stride-64-short rows).
__device__ __forceinline__ int fsw(int row) {
    return (((row & 7) ^ ((row >> 3) & 7)) << 3);
}
// K-row permutation (r6+): physical s-row kperm(s) makes the swapped
// QK^T output land so the PV A-frag assembles in-register.
__device__ __forceinline__ int kperm(int s) {
    return (s & 0x23) | ((s & 0x18) >> 1) | ((s & 4) << 2);
}
// Block-placement XOR-fold (r9): reads + V writes conflict-free, K writes
// 2-way (free).  Verified by r9: conflicts 1.42e7 -> 2.7e6.
__device__ __forceinline__ int bfold(int bi) {
    return bi ^ ((bi >> 3) & 7);
}

// ---- mask bit-pack: (8,1024,1024) int32 -> (8,1024,16) u64 via wave ballot ----
__global__ __launch_bounds__(256)
void pack_mask_kernel(const int* __restrict__ mask, u64* __restrict__ pm)
{
    const int NW = 8 * T_LEN * (T_LEN / 64);   // 131072 words
    const int lane = threadIdx.x & 63;
    const int gw = (int)((blockIdx.x * blockDim.x + threadIdx.x) >> 6);
    const int nw = (int)((gridDim.x * blockDim.x) >> 6);
    for (int w0 = gw; w0 < NW; w0 += 4 * nw) {
        int v[4];
        #pragma unroll
        for (int i = 0; i < 4; ++i) {
            const int w = w0 + i * nw;
            v[i] = (w < NW) ? mask[(size_t)w * 64 + lane] : 0;
        }
        #pragma unroll
        for (int i = 0; i < 4; ++i) {
            const int w = w0 + i * nw;
            const u64 bb = __ballot(v[i] != 0);
            if (lane == 0 && w < NW) pm[w] = bb;
        }
    }
}

// One block = 8 waves = 512 threads: one (head-batch, 256-row Q tile).
// r9 chassis (fragment-major K/V w/ FSTR-pad+bfold, swapped QK^T, kperm,
// P-in-register, packed mask, exp2, dbuf, 1 barrier/iter) + TWO q-groups
// per wave: every K/V fragment read feeds 2 MFMAs -> per-work LDS reads,
// staging VALU/writes, and K/V refetch all halve.  (r4 tried this on the
// fat chassis and lost to VGPR pressure; r9's chassis is 52 VGPR so the
// +~55-VGPR duplication stays under the 128 cap.)
// Q prologue stages 256x64 into the full smem (overlaps buffer B -> one
// extra prologue barrier between Q-frag reads and tile-0 staging).
// launch_bounds (512,2) -> 128-VGPR cap. Spill tripwire: FETCH balloon.
template<bool PM>
__global__ __launch_bounds__(512, 2)
void qkv_attn_kernel(const float* __restrict__ qkv,
                     const int* __restrict__ mask,
                     const u64* __restrict__ pm,
                     const float* __restrict__ qk_bias,
                     float* __restrict__ out)
{
    // 33280 B. prologue: shorts 0..16383 = Q [256][LSTR] swizzled (whole smem).
    // steady: KA=0..4159, VA=4160..8319, KB=8320..12479, VB=12480..16639.
    // epilogue: Os fp32 [128][64] = 32 KB, two passes.
    __shared__ __align__(16) char smem[4 * VOFF * 2];   // 33280 B
    short* Qs = (short*)smem;
    short* KA = Qs;
    short* VA = Qs + VOFF;
    short* KB = Qs + 2 * VOFF;
    short* VB = Qs + 3 * VOFF;
    float* Os = (float*)smem;

    const int tid  = threadIdx.x;
    const int wave = tid >> 6;
    const int lane = tid & 63;
    const int quad = lane >> 4;
    const int l16  = lane & 15;

    const int bh    = blockIdx.x;   // 0..127: consecutive bh -> XCD round-robin
    const int qtile = blockIdx.y;   // 0..3:  stride-128 ids keep a bh on ONE XCD
    const int b     = bh >> 4;
    const int h     = bh & 15;
    const int t0    = qtile * 256;

    const size_t qbase = ((size_t)b * (3 * NH * CH) + (size_t)h * (3 * CH)) * T_LEN;
    const float* kp = qkv + qbase + (size_t)CH * T_LEN;
    const float* vp = qkv + qbase + (size_t)(2 * CH) * T_LEN;

    const float b_l2e  = qk_bias[0] * 1.44269504088896f;  // exp(x)=exp2(x*log2e)
    const float qscale = 0.125f * 1.44269504088896f;      // folded into Q staging

    const int c64   = tid >> 3;        // 0..63 channel row
    const int sse   = (tid & 7) * 8;   // 8-s segment per thread (K/V staging)
    const int tse32 = (tid & 7) * 32;  // Q staging: 32 t per thread

    const float* kpr = kp + (size_t)c64 * T_LEN + sse;
    const float* vpr = vp + (size_t)c64 * T_LEN + sse;

    // fragment-read base (shorts): folded block of this lane, 16B-aligned
    const int bsl8 = bfold(lane) * 8;

    // ---- loop-invariant staging write addresses (fragment-major, folded) ----
    const int hk = c64 >> 5, qk = (c64 >> 3) & 3, coff = c64 & 7;
    int kwadr[8];
    #pragma unroll
    for (int j = 0; j < 8; ++j) {
        const int sp = kperm(sse + j);
        const int fk = (sp >> 4) * 2 + hk;
        const int bi = qk * 16 + (sp & 15);
        kwadr[j] = fk * FSTR + bfold(bi) * 8 + coff;
    }
    const int vwadr = ((c64 >> 4) * 2 + (sse >> 5)) * FSTR
                    + bfold(((sse >> 3) & 3) * 16 + (c64 & 15)) * 8;

    const int tlA = t0 + wave * 32 + l16;        // lane's t, q-group A
    const u64* pmbA = PM ? pm + ((size_t)(h & 7) * T_LEN + tlA) * (T_LEN / 64) : nullptr;
    const u64* pmbB = PM ? pmbA + 16 * (T_LEN / 64) : nullptr;   // +16 rows
    const int* mrowA = mask + (size_t)(h & 7) * T_LEN * T_LEN + (size_t)tlA * T_LEN;
    const int* mrowB = mrowA + 16 * T_LEN;

    // ---- prefetch K/V tile 0 + mask words it=0 ----
    float4 kf0 = *(const float4*)(kpr);
    float4 kf1 = *(const float4*)(kpr + 4);
    float4 vf0 = *(const float4*)(vpr);
    float4 vf1 = *(const float4*)(vpr + 4);
    u64 mnA = PM ? pmbA[0] : 0ULL;
    u64 mnB = PM ? pmbB[0] : 0ULL;

    // ---- stage Q transposed + swizzled + PRE-SCALED (whole 32 KB) ----
    {
        const float* src = qkv + qbase + (size_t)c64 * T_LEN + t0 + tse32;
        #pragma unroll
        for (int k = 0; k < 8; ++k) {
            float4 f = *(const float4*)(src + 4 * k);
            const int t = tse32 + 4 * k;
            Qs[(t + 0) * LSTR + (c64 ^ fsw(t + 0))] = f2bf(f.x * qscale);
            Qs[(t + 1) * LSTR + (c64 ^ fsw(t + 1))] = f2bf(f.y * qscale);
            Qs[(t + 2) * LSTR + (c64 ^ fsw(t + 2))] = f2bf(f.z * qscale);
            Qs[(t + 3) * LSTR + (c64 ^ fsw(t + 3))] = f2bf(f.w * qscale);
        }
    }
    __syncthreads();

    // ---- loop-invariant Q fragments, both q-groups ----
    const int qrA = wave * 32 + l16;
    const int qrB = qrA + 16;
    const short8 aq00 = *(const short8*)&Qs[qrA * LSTR + ((quad * 8)      ^ fsw(qrA))];
    const short8 aq01 = *(const short8*)&Qs[qrA * LSTR + ((quad * 8 + 32) ^ fsw(qrA))];
    const short8 aq10 = *(const short8*)&Qs[qrB * LSTR + ((quad * 8)      ^ fsw(qrB))];
    const short8 aq11 = *(const short8*)&Qs[qrB * LSTR + ((quad * 8 + 32) ^ fsw(qrB))];
    __syncthreads();   // Q region is reused by buffer B below

    // ---- stage K/V tile 0 into buffer B ----
    {
        const float kv[8] = {kf0.x,kf0.y,kf0.z,kf0.w,kf1.x,kf1.y,kf1.z,kf1.w};
        #pragma unroll
        for (int i2 = 0; i2 < 4; ++i2) {
            const unsigned w = cvt_pk_bf16(kv[2*i2], kv[2*i2+1]);
            KB[kwadr[2*i2]]   = (short)(w & 0xFFFFu);
            KB[kwadr[2*i2+1]] = (short)(w >> 16);
        }
        uint4 vw;
        vw.x = cvt_pk_bf16(vf0.x, vf0.y);
        vw.y = cvt_pk_bf16(vf0.z, vf0.w);
        vw.z = cvt_pk_bf16(vf1.x, vf1.y);
        vw.w = cvt_pk_bf16(vf1.z, vf1.w);
        *(uint4*)&VB[vwadr] = vw;
    }
    __syncthreads();

    const short one_bf = (short)0x3F80;
    const short8 ones8 = (short8){one_bf, one_bf, one_bf, one_bf,
                                  one_bf, one_bf, one_bf, one_bf};

    floatx4 o0[4], o1[4], ol0, ol1;
    #pragma unroll
    for (int i = 0; i < 4; ++i) { o0[i] = (floatx4){0.f,0.f,0.f,0.f};
                                  o1[i] = (floatx4){0.f,0.f,0.f,0.f}; }
    ol0 = (floatx4){0.f,0.f,0.f,0.f};
    ol1 = (floatx4){0.f,0.f,0.f,0.f};

    for (int it = 0; it < 16; ++it) {
        const int s0 = it * 64;
        // even it -> compute from B (tile0 staged there), stage next into A
        const short* Kc = (it & 1) ? KA : KB;
        const short* Vc = (it & 1) ? VA : VB;
        short* Kd = (it & 1) ? KB : KA;
        short* Vd = (it & 1) ? VB : VA;

        const u64 mcA = mnA, mcB = mnB;
        // issue next-tile K/V global loads + mask words (hidden under compute)
        if (it < 15) {
            kf0 = *(const float4*)(kpr + s0 + 64);
            kf1 = *(const float4*)(kpr + s0 + 68);
            vf0 = *(const float4*)(vpr + s0 + 64);
            vf1 = *(const float4*)(vpr + s0 + 68);
            if (PM) { mnA = pmbA[it + 1]; mnB = pmbB[it + 1]; }
        }

        // ---- S^T = K Q (scale/bias pre-folded) -> P = exp2 masked, in-reg;
        //      each bk fragment read feeds BOTH q-groups ----
        unsigned paA[8], paB[8];
        #pragma unroll
        for (int sub = 0; sub < 4; ++sub) {
            const short8 bk0 = *(const short8*)&Kc[(sub * 2 + 0) * FSTR + bsl8];
            const short8 bk1 = *(const short8*)&Kc[(sub * 2 + 1) * FSTR + bsl8];
            floatx4 accA = (floatx4){b_l2e, b_l2e, b_l2e, b_l2e};
            floatx4 accB = (floatx4){b_l2e, b_l2e, b_l2e, b_l2e};
            accA = __builtin_amdgcn_mfma_f32_16x16x32_bf16(bk0, aq00, accA, 0, 0, 0);
            accA = __builtin_amdgcn_mfma_f32_16x16x32_bf16(bk1, aq01, accA, 0, 0, 0);
            accB = __builtin_amdgcn_mfma_f32_16x16x32_bf16(bk0, aq10, accB, 0, 0, 0);
            accB = __builtin_amdgcn_mfma_f32_16x16x32_bf16(bk1, aq11, accB, 0, 0, 0);
            // original s for (sub, quad, r): 32*(sub>>1) + 8*quad + 4*(sub&1) + r
            const int sbase = 32 * (sub >> 1) + 4 * (sub & 1) + 8 * quad;
            unsigned msA = 0, msB = 0;
            if (PM) {
                msA = (unsigned)(mcA >> sbase) & 0xFu;
                msB = (unsigned)(mcB >> sbase) & 0xFu;
            }
            float fA[4], fB[4];
            #pragma unroll
            for (int r = 0; r < 4; ++r) {
                bool keepA, keepB;
                if (PM) { keepA = ((msA >> r) & 1u) != 0;
                          keepB = ((msB >> r) & 1u) != 0; }
                else    { keepA = mrowA[s0 + sbase + r] != 0;
                          keepB = mrowB[s0 + sbase + r] != 0; }
                const float eA = __builtin_amdgcn_exp2f(accA[r]);
                const float eB = __builtin_amdgcn_exp2f(accB[r]);
                fA[r] = keepA ? eA : 0.f;
                fB[r] = keepB ? eB : 0.f;
            }
            paA[sub * 2 + 0] = cvt_pk_bf16(fA[0], fA[1]);
            paA[sub * 2 + 1] = cvt_pk_bf16(fA[2], fA[3]);
            paB[sub * 2 + 0] = cvt_pk_bf16(fB[0], fB[1]);
            paB[sub * 2 + 1] = cvt_pk_bf16(fB[2], fB[3]);
        }
        const short8 ap0A = *(const short8*)&paA[0];
        const short8 ap1A = *(const short8*)&paA[4];
        const short8 ap0B = *(const short8*)&paB[0];
        const short8 ap1B = *(const short8*)&paB[4];

        // ---- O += P V ; l += P . 1  (each bv fragment feeds BOTH groups) ----
        __builtin_amdgcn_s_setprio(1);
        #pragma unroll
        for (int csub = 0; csub < 4; ++csub) {
            const short8 bv0 = *(const short8*)&Vc[(csub * 2 + 0) * FSTR + bsl8];
            const short8 bv1 = *(const short8*)&Vc[(csub * 2 + 1) * FSTR + bsl8];
            o0[csub] = __builtin_amdgcn_mfma_f32_16x16x32_bf16(ap0A, bv0, o0[csub], 0, 0, 0);
            o0[csub] = __builtin_amdgcn_mfma_f32_16x16x32_bf16(ap1A, bv1, o0[csub], 0, 0, 0);
            o1[csub] = __builtin_amdgcn_mfma_f32_16x16x32_bf16(ap0B, bv0, o1[csub], 0, 0, 0);
            o1[csub] = __builtin_amdgcn_mfma_f32_16x16x32_bf16(ap1B, bv1, o1[csub], 0, 0, 0);
        }
        ol0 = __builtin_amdgcn_mfma_f32_16x16x32_bf16(ap0A, ones8, ol0, 0, 0, 0);
        ol0 = __builtin_amdgcn_mfma_f32_16x16x32_bf16(ap1A, ones8, ol0, 0, 0, 0);
        ol1 = __builtin_amdgcn_mfma_f32_16x16x32_bf16(ap0B, ones8, ol1, 0, 0, 0);
        ol1 = __builtin_amdgcn_mfma_f32_16x16x32_bf16(ap1B, ones8, ol1, 0, 0, 0);
        __builtin_amdgcn_s_setprio(0);

        // ---- write prefetched next tile into the other buffer; one barrier ----
        if (it < 15) {
            const float kv[8] = {kf0.x,kf0.y,kf0.z,kf0.w,kf1.x,kf1.y,kf1.z,kf1.w};
            #pragma unroll
            for (int i2 = 0; i2 < 4; ++i2) {
                const unsigned w = cvt_pk_bf16(kv[2*i2], kv[2*i2+1]);
                Kd[kwadr[2*i2]]   = (short)(w & 0xFFFFu);
                Kd[kwadr[2*i2+1]] = (short)(w >> 16);
            }
            uint4 vw;
            vw.x = cvt_pk_bf16(vf0.x, vf0.y);
            vw.y = cvt_pk_bf16(vf0.z, vf0.w);
            vw.z = cvt_pk_bf16(vf1.x, vf1.y);
            vw.w = cvt_pk_bf16(vf1.z, vf1.w);
            #pragma unroll
            for (int i = 0; i < 4; ++i) { }
            *(uint4*)&Vd[vwadr] = vw;
            __syncthreads();
        }
    }

    // ---- epilogue: two passes (one per q-group) through Os fp32 [128][64];
    //      double-XOR swizzle -> max 2-way on both sides ----
    __syncthreads();   // all compute done before Os overwrites K/V buffers
    float invA[4], invB[4];
    #pragma unroll
    for (int r = 0; r < 4; ++r) {
        invA[r] = (ol0[r] > 0.f) ? 1.f / ol0[r] : 0.f;
        invB[r] = (ol1[r] > 0.f) ? 1.f / ol1[r] : 0.f;
    }
    const int okeyw = (wave << 3) ^ (quad << 4);
    const int tse16 = (tid & 7) * 16;
    float* dstb = out + ((size_t)b * (NH * CH) + (size_t)h * CH + c64) * T_LEN
                + t0 + (tid & 7) * 32;

    #pragma unroll
    for (int pass = 0; pass < 2; ++pass) {
        #pragma unroll
        for (int csub = 0; csub < 4; ++csub)
            #pragma unroll
            for (int r = 0; r < 4; ++r) {
                const float v = (pass == 0) ? o0[csub][r] * invA[r]
                                            : o1[csub][r] * invB[r];
                Os[(wave * 16 + quad * 4 + r) * 64 + ((csub * 16 + l16) ^ okeyw)] = v;
            }
        __syncthreads();
        {
            float* dst = dstb + pass * 16;
            #pragma unroll
            for (int k = 0; k < 4; ++k) {
                float4 f;
                #pragma unroll
                for (int j = 0; j < 4; ++j) {
                    const int rl = tse16 + 4 * k + j;
                    const int ok = ((rl >> 4) << 3) ^ (((rl >> 2) & 3) << 4);
                    ((float*)&f)[j] = Os[rl * 64 + (c64 ^ ok)];
                }
                *(float4*)(dst + 4 * k) = f;
            }
        }
        if (pass == 0) __syncthreads();
    }
}

extern "C" void kernel_launch(void* const* d_in, const int* in_sizes, int n_in,
                              void* d_out, int out_size, void* d_ws, size_t ws_size,
                              hipStream_t stream) {
    const float* qkv     = (const float*)d_in[0];
    const int*   mask    = (const int*)d_in[1];
    const float* qk_bias = (const float*)d_in[2];
    float*       out     = (float*)d_out;

    const size_t pm_bytes = (size_t)8 * T_LEN * (T_LEN / 64) * sizeof(u64);  // 1 MiB
    u64* pm = nullptr;
    if (d_ws && ws_size >= pm_bytes) {
        pm = (u64*)d_ws;
        pack_mask_kernel<<<2048, 256, 0, stream>>>(mask, pm);
    }

    dim3 grid(8 * NH, T_LEN / 256);  // (head-batches, q-tiles) = (128, 4)
    if (pm) qkv_attn_kernel<true ><<<grid, 512, 0, stream>>>(qkv, mask, pm, qk_bias, out);
    else    qkv_attn_kernel<false><<<grid, 512, 0, stream>>>(qkv, mask, nullptr, qk_bias, out);
}

// Round 11
// 229.027 us; speedup vs baseline: 1.0647x; 1.0647x over previous
//
#include <hip/hip_runtime.h>
#include <hip/hip_bf16.h>

#define T_LEN 1024
#define NH    16
#define CH    64
#define LSTR  64        // Q-prologue LDS row stride in shorts (128 B)
#define FSTR  520       // fragment stride in shorts (512 + 8 pad)
#define VOFF  (8 * FSTR)   // one K-or-V buffer in shorts (4160 = 8320 B)

typedef __attribute__((ext_vector_type(8))) short short8;
typedef __attribute__((ext_vector_type(4))) float floatx4;
typedef unsigned long long u64;

__device__ __forceinline__ short f2bf(float x) {
    __hip_bfloat16 b = __float2bfloat16(x);   // RNE (prologue-only scalar path)
    return *(short*)&b;
}
// HW packed conversion: dst.lo16 = bf16(lo), dst.hi16 = bf16(hi).
__device__ __forceinline__ unsigned cvt_pk_bf16(float lo, float hi) {
    unsigned r;
    asm("v_cvt_pk_bf16_f32 %0, %1, %2" : "=v"(r) : "v"(lo), "v"(hi));
    return r;
}
// XOR block-swizzle for the Q prologue tile (stride-64-short rows).
__device__ __forceinline__ int fsw(int row) {
    return (((row & 7) ^ ((row >> 3) & 7)) << 3);
}
// K-row permutation (r6+): physical s-row kperm(s) makes the swapped
// QK^T output land so the PV A-frag assembles in-register.
__device__ __forceinline__ int kperm(int s) {
    return (s & 0x23) | ((s & 0x18) >> 1) | ((s & 4) << 2);
}
// Block-placement XOR-fold (r9): frag reads + V writes conflict-free,
// K writes 2-way (free).  Verified: conflicts 1.42e7 -> 2.7e6.
__device__ __forceinline__ int bfold(int bi) {
    return bi ^ ((bi >> 3) & 7);
}

// ---- mask bit-pack: (8,1024,1024) int32 -> (8,1024,16) u64 via wave ballot ----
__global__ __launch_bounds__(256)
void pack_mask_kernel(const int* __restrict__ mask, u64* __restrict__ pm)
{
    const int NW = 8 * T_LEN * (T_LEN / 64);   // 131072 words
    const int lane = threadIdx.x & 63;
    const int gw = (int)((blockIdx.x * blockDim.x + threadIdx.x) >> 6);
    const int nw = (int)((gridDim.x * blockDim.x) >> 6);
    for (int w0 = gw; w0 < NW; w0 += 4 * nw) {
        int v[4];
        #pragma unroll
        for (int i = 0; i < 4; ++i) {
            const int w = w0 + i * nw;
            v[i] = (w < NW) ? mask[(size_t)w * 64 + lane] : 0;
        }
        #pragma unroll
        for (int i = 0; i < 4; ++i) {
            const int w = w0 + i * nw;
            const u64 bb = __ballot(v[i] != 0);
            if (lane == 0 && w < NW) pm[w] = bb;
        }
    }
}

// QK+softmax of one tile -> P fragment in registers (r9's body, macro'd).
#define QK_TILE(TILE, KC, MW, PDST) do {                                      \
    _Pragma("unroll")                                                         \
    for (int sub = 0; sub < 4; ++sub) {                                       \
        const short8 bk0 = *(const short8*)&(KC)[(sub*2+0)*FSTR + bsl8];      \
        const short8 bk1 = *(const short8*)&(KC)[(sub*2+1)*FSTR + bsl8];      \
        floatx4 acc = (floatx4){b_l2e, b_l2e, b_l2e, b_l2e};                  \
        acc = __builtin_amdgcn_mfma_f32_16x16x32_bf16(bk0, aq0, acc, 0,0,0);  \
        acc = __builtin_amdgcn_mfma_f32_16x16x32_bf16(bk1, aq1, acc, 0,0,0);  \
        const int sbase = 32*(sub>>1) + 4*(sub&1) + 8*quad;                   \
        unsigned mseg = 0;                                                    \
        if (PM) mseg = (unsigned)((MW) >> sbase) & 0xFu;                      \
        float pf[4];                                                          \
        _Pragma("unroll")                                                     \
        for (int r = 0; r < 4; ++r) {                                         \
            bool keep;                                                        \
            if (PM) keep = ((mseg >> r) & 1u) != 0;                           \
            else    keep = mrow[(TILE)*64 + sbase + r] != 0;                  \
            const float e = __builtin_amdgcn_exp2f(acc[r]);                   \
            pf[r] = keep ? e : 0.f;                                           \
        }                                                                     \
        (PDST)[sub*2+0] = cvt_pk_bf16(pf[0], pf[1]);                          \
        (PDST)[sub*2+1] = cvt_pk_bf16(pf[2], pf[3]);                          \
    }                                                                         \
} while (0)

// PV accumulate of one tile from a register P fragment.
#define PV_TILE(VC, PSRC) do {                                                \
    const short8 ap0 = *(const short8*)&(PSRC)[0];                            \
    const short8 ap1 = *(const short8*)&(PSRC)[4];                            \
    __builtin_amdgcn_s_setprio(1);                                            \
    _Pragma("unroll")                                                         \
    for (int csub = 0; csub < 4; ++csub) {                                    \
        const short8 bv0 = *(const short8*)&(VC)[(csub*2+0)*FSTR + bsl8];     \
        const short8 bv1 = *(const short8*)&(VC)[(csub*2+1)*FSTR + bsl8];     \
        o[csub] = __builtin_amdgcn_mfma_f32_16x16x32_bf16(ap0, bv0, o[csub],0,0,0); \
        o[csub] = __builtin_amdgcn_mfma_f32_16x16x32_bf16(ap1, bv1, o[csub],0,0,0); \
    }                                                                         \
    ol = __builtin_amdgcn_mfma_f32_16x16x32_bf16(ap0, ones8, ol, 0,0,0);      \
    ol = __builtin_amdgcn_mfma_f32_16x16x32_bf16(ap1, ones8, ol, 0,0,0);      \
    __builtin_amdgcn_s_setprio(0);                                            \
} while (0)

// cvt + LDS write of a staged K/V tile (fragment-major, folded).
#define KV_WRITE(KD, VD, A0, A1, B0, B1) do {                                 \
    const float kv_[8] = {(A0).x,(A0).y,(A0).z,(A0).w,                        \
                          (A1).x,(A1).y,(A1).z,(A1).w};                       \
    _Pragma("unroll")                                                         \
    for (int i2 = 0; i2 < 4; ++i2) {                                          \
        const unsigned w = cvt_pk_bf16(kv_[2*i2], kv_[2*i2+1]);               \
        (KD)[kwadr[2*i2]]   = (short)(w & 0xFFFFu);                           \
        (KD)[kwadr[2*i2+1]] = (short)(w >> 16);                               \
    }                                                                         \
    uint4 vw_;                                                                \
    vw_.x = cvt_pk_bf16((B0).x, (B0).y);                                      \
    vw_.y = cvt_pk_bf16((B0).z, (B0).w);                                      \
    vw_.z = cvt_pk_bf16((B1).x, (B1).y);                                      \
    vw_.w = cvt_pk_bf16((B1).z, (B1).w);                                      \
    *(uint4*)&(VD)[vwadr] = vw_;                                              \
} while (0)

// One block = 8 waves = 512 threads: one (head-batch, 128-row Q tile).
// r9 chassis + CROSS-TILE SOFTWARE PIPELINE: each barrier window runs
// {QK+softmax(tile s+1) || PV(tile s) || stage(tile s+2)} -> the ds_read-K
// latency + QK MFMAs + exp chain hide under PV's 10 independent MFMAs.
// (r9 diagnosis: no pipe >56% busy, occupancy fixed -> latency-bound; r10
// re-confirmed that cutting wave count makes it worse.)  K double-buffered,
// V TRIPLE-buffered (PV lags the writer by 2 steps); 1 barrier/step.
// 15-step loop fully unrolled so pa[2] ping-pong and V[s%3] are static.
// launch_bounds (512,2) -> 128-VGPR cap (est ~105). Spill tripwire: FETCH.
template<bool PM>
__global__ __launch_bounds__(512, 2)
void qkv_attn_kernel(const float* __restrict__ qkv,
                     const int* __restrict__ mask,
                     const u64* __restrict__ pm,
                     const float* __restrict__ qk_bias,
                     float* __restrict__ out)
{
    // 41600 B = 5 buffers x 4160 shorts: K0|K1|V0|V1|V2  (tile i -> K[i%2], V[i%3]).
    // prologue: shorts 0..8191 = Q [128][LSTR] swizzled (overlaps K0|K1).
    // epilogue: Os fp32 [128][64] = 32 KB (overlaps K0..V1).
    __shared__ __align__(16) char smem[5 * VOFF * 2];
    short* Qs = (short*)smem;
    short* const Kb[2] = { Qs,            Qs + VOFF };
    short* const Vb[3] = { Qs + 2 * VOFF, Qs + 3 * VOFF, Qs + 4 * VOFF };
    float* Os = (float*)smem;

    const int tid  = threadIdx.x;
    const int wave = tid >> 6;
    const int lane = tid & 63;
    const int quad = lane >> 4;
    const int l16  = lane & 15;

    const int bh    = blockIdx.x;   // 0..127: consecutive bh -> XCD round-robin
    const int qtile = blockIdx.y;   // 0..7:  stride-128 ids keep a bh on ONE XCD
    const int b     = bh >> 4;
    const int h     = bh & 15;
    const int t0    = qtile * 128;

    const size_t qbase = ((size_t)b * (3 * NH * CH) + (size_t)h * (3 * CH)) * T_LEN;
    const float* kp = qkv + qbase + (size_t)CH * T_LEN;
    const float* vp = qkv + qbase + (size_t)(2 * CH) * T_LEN;

    const float b_l2e  = qk_bias[0] * 1.44269504088896f;  // exp(x)=exp2(x*log2e)
    const float qscale = 0.125f * 1.44269504088896f;      // folded into Q staging

    const int c64 = tid >> 3;          // 0..63 channel row
    const int sse = (tid & 7) * 8;     // 8-s segment per thread (K/V staging)
    const int tse = (tid & 7) * 16;    // Q staging segment

    const float* kpr = kp + (size_t)c64 * T_LEN + sse;
    const float* vpr = vp + (size_t)c64 * T_LEN + sse;

    // fragment-read base (shorts): folded block of this lane, 16B-aligned
    const int bsl8 = bfold(lane) * 8;

    // ---- loop-invariant staging write addresses (fragment-major, folded) ----
    const int hk = c64 >> 5, qk = (c64 >> 3) & 3, coff = c64 & 7;
    int kwadr[8];
    #pragma unroll
    for (int j = 0; j < 8; ++j) {
        const int sp = kperm(sse + j);
        const int fk = (sp >> 4) * 2 + hk;
        const int bi = qk * 16 + (sp & 15);
        kwadr[j] = fk * FSTR + bfold(bi) * 8 + coff;
    }
    const int vwadr = ((c64 >> 4) * 2 + (sse >> 5)) * FSTR
                    + bfold(((sse >> 3) & 3) * 16 + (c64 & 15)) * 8;

    const int tl = t0 + wave * 16 + l16;   // lane's own t (mask row)
    const u64* pmb = PM ? pm + ((size_t)(h & 7) * T_LEN + tl) * (T_LEN / 64) : nullptr;
    const int* mrow = mask + (size_t)(h & 7) * T_LEN * T_LEN + (size_t)tl * T_LEN;

    // ---- prefetch tiles 0 and 1 + mask words ----
    float4 kf0 = *(const float4*)(kpr);
    float4 kf1 = *(const float4*)(kpr + 4);
    float4 vf0 = *(const float4*)(vpr);
    float4 vf1 = *(const float4*)(vpr + 4);
    float4 kg0 = *(const float4*)(kpr + 64);
    float4 kg1 = *(const float4*)(kpr + 68);
    float4 vg0 = *(const float4*)(vpr + 64);
    float4 vg1 = *(const float4*)(vpr + 68);
    u64 m0     = PM ? pmb[0] : 0ULL;
    u64 m_next = PM ? pmb[1] : 0ULL;

    // ---- stage Q transposed + swizzled + PRE-SCALED (shorts 0..8191) ----
    {
        const float* src = qkv + qbase + (size_t)c64 * T_LEN + t0 + tse;
        #pragma unroll
        for (int k = 0; k < 4; ++k) {
            float4 f = *(const float4*)(src + 4 * k);
            const int t = tse + 4 * k;
            Qs[(t + 0) * LSTR + (c64 ^ fsw(t + 0))] = f2bf(f.x * qscale);
            Qs[(t + 1) * LSTR + (c64 ^ fsw(t + 1))] = f2bf(f.y * qscale);
            Qs[(t + 2) * LSTR + (c64 ^ fsw(t + 2))] = f2bf(f.z * qscale);
            Qs[(t + 3) * LSTR + (c64 ^ fsw(t + 3))] = f2bf(f.w * qscale);
        }
    }
    __syncthreads();

    // ---- loop-invariant Q fragments (B-operand of swapped QK^T) ----
    const int qrow = wave * 16 + l16;
    const short8 aq0 = *(const short8*)&Qs[qrow * LSTR + ((quad * 8)      ^ fsw(qrow))];
    const short8 aq1 = *(const short8*)&Qs[qrow * LSTR + ((quad * 8 + 32) ^ fsw(qrow))];
    __syncthreads();   // Q region reused by K0/K1 below

    // ---- stage tiles 0,1 into K0/V0, K1/V1 ----
    KV_WRITE(Kb[0], Vb[0], kf0, kf1, vf0, vf1);
    KV_WRITE(Kb[1], Vb[1], kg0, kg1, vg0, vg1);
    __syncthreads();

    const short one_bf = (short)0x3F80;
    const short8 ones8 = (short8){one_bf, one_bf, one_bf, one_bf,
                                  one_bf, one_bf, one_bf, one_bf};

    floatx4 o[4], ol;
    #pragma unroll
    for (int i = 0; i < 4; ++i) o[i] = (floatx4){0.f, 0.f, 0.f, 0.f};
    ol = (floatx4){0.f, 0.f, 0.f, 0.f};

    // ---- pipeline prime: QK(0) -> pa[0]; barrier before step 0 writes K0 ----
    unsigned pa[2][8];
    QK_TILE(0, Kb[0], m0, pa[0]);
    __syncthreads();

    // ---- steady state: {QK(s+1) || PV(s) || stage(s+2)}; 1 barrier/step ----
    #pragma unroll
    for (int s = 0; s < 15; ++s) {
        if (s + 2 <= 15) {
            kf0 = *(const float4*)(kpr + (s + 2) * 64);
            kf1 = *(const float4*)(kpr + (s + 2) * 64 + 4);
            vf0 = *(const float4*)(vpr + (s + 2) * 64);
            vf1 = *(const float4*)(vpr + (s + 2) * 64 + 4);
        }
        const u64 m_use = m_next;                  // mask for tile s+1
        if (PM && s + 2 <= 15) m_next = pmb[s + 2];

        QK_TILE(s + 1, Kb[(s + 1) & 1], m_use, pa[(s + 1) & 1]);
        PV_TILE(Vb[s % 3], pa[s & 1]);

        if (s + 2 <= 15)
            KV_WRITE(Kb[s & 1], Vb[(s + 2) % 3], kf0, kf1, vf0, vf1);
        __syncthreads();
    }
    PV_TILE(Vb[15 % 3], pa[15 & 1]);               // drain: PV(15)

    // ---- epilogue: Os fp32 [128][64] (32 KB); double-XOR swizzle ----
    __syncthreads();   // all compute done before Os overwrites K/V buffers
    float inv[4];
    #pragma unroll
    for (int r = 0; r < 4; ++r) inv[r] = (ol[r] > 0.f) ? 1.f / ol[r] : 0.f;
    const int okeyw = (wave << 3) ^ (quad << 4);
    #pragma unroll
    for (int csub = 0; csub < 4; ++csub)
        #pragma unroll
        for (int r = 0; r < 4; ++r)
            Os[(wave * 16 + quad * 4 + r) * 64 + ((csub * 16 + l16) ^ okeyw)] =
                o[csub][r] * inv[r];
    __syncthreads();
    {
        float* dst = out + ((size_t)b * (NH * CH) + (size_t)h * CH + c64) * T_LEN
                   + t0 + tse;
        #pragma unroll
        for (int k = 0; k < 4; ++k) {
            float4 f;
            #pragma unroll
            for (int j = 0; j < 4; ++j) {
                const int rl = tse + 4 * k + j;
                const int ok = ((rl >> 4) << 3) ^ (((rl >> 2) & 3) << 4);
                ((float*)&f)[j] = Os[rl * 64 + (c64 ^ ok)];
            }
            *(float4*)(dst + 4 * k) = f;
        }
    }
}

extern "C" void kernel_launch(void* const* d_in, const int* in_sizes, int n_in,
                              void* d_out, int out_size, void* d_ws, size_t ws_size,
                              hipStream_t stream) {
    const float* qkv     = (const float*)d_in[0];
    const int*   mask    = (const int*)d_in[1];
    const float* qk_bias = (const float*)d_in[2];
    float*       out     = (float*)d_out;

    const size_t pm_bytes = (size_t)8 * T_LEN * (T_LEN / 64) * sizeof(u64);  // 1 MiB
    u64* pm = nullptr;
    if (d_ws && ws_size >= pm_bytes) {
        pm = (u64*)d_ws;
        pack_mask_kernel<<<2048, 256, 0, stream>>>(mask, pm);
    }

    dim3 grid(8 * NH, T_LEN / 128);  // (head-batches, q-tiles) = (128, 8)
    if (pm) qkv_attn_kernel<true ><<<grid, 512, 0, stream>>>(qkv, mask, pm, qk_bias, out);
    else    qkv_attn_kernel<false><<<grid, 512, 0, stream>>>(qkv, mask, nullptr, qk_bias, out);
}